// Round 9
// baseline (237.468 us; speedup 1.0000x reference)
//
#include <hip/hip_runtime.h>

// ---- problem constants ----
#define HWN 4096
#define CCH 512
#define NHEAD 8
#define DHD 64
#define NBATCH 2
#define QK_SCALE 0.35355339059327373f   // 64^-0.25
#define LOG2E    1.4426950408889634f

using floatx4 = __attribute__((ext_vector_type(4))) float;
using bf16x8  = __attribute__((ext_vector_type(8))) short;
using bf16x4  = __attribute__((ext_vector_type(4))) short;

__device__ __forceinline__ unsigned short f2b(float f) {
  union { float f; unsigned u; } x; x.f = f;
  unsigned r = x.u + 0x7FFFu + ((x.u >> 16) & 1u);
  return (unsigned short)(r >> 16);
}

__device__ __forceinline__ float b2f(unsigned short u) {
  union { unsigned u; float f; } x; x.u = ((unsigned)u) << 16;
  return x.f;
}

__device__ __forceinline__ float fast_exp2(float x) {
#if __has_builtin(__builtin_amdgcn_exp2f)
  return __builtin_amdgcn_exp2f(x);
#else
  return __expf(x * 0.69314718056f);
#endif
}

// pack bf16(lo),bf16(hi) from two floats in ONE v_perm_b32 (truncating round)
__device__ __forceinline__ unsigned pack_bf16_trunc(float lo, float hi) {
  return __builtin_amdgcn_perm(__float_as_uint(hi), __float_as_uint(lo), 0x07060302u);
}

// ------- 1+2 merged. blocks [0,4103): weight prep; [4103,4615): GN stats -------
__global__ __launch_bounds__(256) void prep_gn(
    const float* __restrict__ x, float* __restrict__ stat,
    const float* __restrict__ wq, const float* __restrict__ wk,
    const float* __restrict__ wv, const float* __restrict__ wp,
    const float* __restrict__ bq, const float* __restrict__ bk,
    const float* __restrict__ bv,
    unsigned short* __restrict__ Wqkv, unsigned short* __restrict__ Wp,
    float* __restrict__ bqkv) {
  if (blockIdx.x >= 4103) {
    // GroupNorm partial sums: 512 virtual blocks = (64 groups x 8 parts)
    int idx = blockIdx.x - 4103;
    int bg = idx & 63, part = idx >> 6;
    const float4* p = (const float4*)(x + (size_t)bg * 65536) + part * 2048;
    float s = 0.f, ss = 0.f;
    for (int i = threadIdx.x; i < 2048; i += 256) {
      float4 v = p[i];
      s  += v.x + v.y + v.z + v.w;
      ss += v.x*v.x + v.y*v.y + v.z*v.z + v.w*v.w;
    }
    for (int off = 32; off; off >>= 1) {
      s  += __shfl_xor(s, off);
      ss += __shfl_xor(ss, off);
    }
    __shared__ float red[8];
    int w = threadIdx.x >> 6;
    if ((threadIdx.x & 63) == 0) { red[w] = s; red[4 + w] = ss; }
    __syncthreads();
    if (threadIdx.x == 0) {
      float S  = red[0] + red[1] + red[2] + red[3];
      float SS = red[4] + red[5] + red[6] + red[7];
      atomicAdd(&stat[bg], S);
      atomicAdd(&stat[64 + bg], SS);
    }
    return;
  }
  // weight prep: fp32 -> bf16, fold SCALE (and log2e into q)
  int i = blockIdx.x * 256 + threadIdx.x;
  if (i < 786432) {                       // Wqkv: rows 0-511 q, 512-1023 k, 1024-1535 v
    int row = i >> 9;
    float v;
    if (row < 512)       v = wq[i] * (QK_SCALE * LOG2E);
    else if (row < 1024) v = wk[i - 262144] * QK_SCALE;
    else                 v = wv[i - 524288];
    Wqkv[i] = f2b(v);
  } else if (i < 1048576) {
    Wp[i - 786432] = f2b(wp[i - 786432]);
  } else if (i < 1050112) {
    int j = i - 1048576;
    float v = (j < 512) ? bq[j] * (QK_SCALE * LOG2E)
            : (j < 1024) ? bk[j - 512] * QK_SCALE
            : bv[j - 1024];
    bqkv[j] = v;
  }
}

// ---------------- 3. normalize + transpose to t[(b*4096+p)*512 + c] bf16 ----------------
__global__ __launch_bounds__(256) void gn_apply(
    const float* __restrict__ x, const float* __restrict__ stat,
    const float* __restrict__ gnw, const float* __restrict__ gnb,
    unsigned short* __restrict__ t) {
  int pt = blockIdx.x & 63;
  int ct = (blockIdx.x >> 6) & 7;
  int b  = blockIdx.x >> 9;
  int c0 = ct * 64, p0 = pt * 64;
  __shared__ float tile[64][68];          // pad 68: bank shift 4/row, float4-aligned
  int tid = threadIdx.x;
  for (int pp = 0; pp < 4; ++pp) {
    int f = (pp * 256 + tid) * 4;
    int cl = f >> 6, pl = f & 63;
    int c = c0 + cl;
    float4 v = *(const float4*)(x + ((size_t)(b * 512 + c)) * 4096 + p0 + pl);
    int g = c >> 4;
    float S    = stat[b * 32 + g];
    float SS   = stat[64 + b * 32 + g];
    float mean = S * (1.f / 65536.f);
    float var  = SS * (1.f / 65536.f) - mean * mean;
    float rstd = rsqrtf(var + 1e-5f);
    float w  = gnw[c] * rstd;
    float bb = gnb[c] - mean * w;
    tile[cl][pl + 0] = v.x * w + bb;
    tile[cl][pl + 1] = v.y * w + bb;
    tile[cl][pl + 2] = v.z * w + bb;
    tile[cl][pl + 3] = v.w * w + bb;
  }
  __syncthreads();
  for (int pp = 0; pp < 2; ++pp) {
    int f = (pp * 256 + tid) * 8;
    int pl = f >> 6, cl = f & 63;
    unsigned short u[8];
#pragma unroll
    for (int j = 0; j < 8; ++j) u[j] = f2b(tile[cl + j][pl]);
    *(uint4*)(t + ((size_t)(b * 4096 + p0 + pl)) * 512 + c0 + cl) = *(uint4*)u;
  }
}

// ---------------- 4. QKV GEMM ----------------
// q: [(bh*4096+p)*64+d] bf16 ; v: TRANSPOSED [bh][d][4096] bf16 ;
// K: FRAG-MAJOR Kp[bh][kb(32)][ig(8)][half(2)][lane(64)x8] bf16 — each 1 KB
// chunk is exactly one wave-wide A-frag load for attn (lane-contiguous 16 B).
// Chunk semantics: lane l (quad=l>>4, m16=l&15), byte j -> K[key = kb*128 +
// (ig>>1)*32 + (ig&1)*4 + (m16>>2)*8 + (m16&3)][d = half*32 + quad*8 + j/2].
__global__ __launch_bounds__(256) void gemm_qkv(
    const unsigned short* __restrict__ t, const unsigned short* __restrict__ Wqkv,
    const float* __restrict__ bqkv,
    unsigned short* __restrict__ qo, unsigned short* __restrict__ Kp,
    unsigned short* __restrict__ vo) {
  int M0 = blockIdx.x * 64;   // pixel 0..8128
  int N0 = blockIdx.y * 64;   // outch 0..1472
  __shared__ unsigned short At[64][72];
  __shared__ unsigned short Bt[64][72];
  int tid = threadIdx.x, w = tid >> 6, l = tid & 63;
  int quad = l >> 4, m16 = l & 15;
  floatx4 acc[4] = {};
  for (int k0 = 0; k0 < 512; k0 += 64) {
    __syncthreads();
#pragma unroll
    for (int pp = 0; pp < 2; ++pp) {
      int f = (pp * 256 + tid) * 8;
      int r = f >> 6, c = f & 63;
      *(uint4*)&At[r][c] = *(const uint4*)(t    + (size_t)(M0 + r) * 512 + k0 + c);
      *(uint4*)&Bt[r][c] = *(const uint4*)(Wqkv + (size_t)(N0 + r) * 512 + k0 + c);
    }
    __syncthreads();
    bf16x8 af0 = *(const bf16x8*)&At[w * 16 + m16][quad * 8];
    bf16x8 af1 = *(const bf16x8*)&At[w * 16 + m16][32 + quad * 8];
#pragma unroll
    for (int nt = 0; nt < 4; ++nt) {
      bf16x8 b0 = *(const bf16x8*)&Bt[nt * 16 + m16][quad * 8];
      bf16x8 b1 = *(const bf16x8*)&Bt[nt * 16 + m16][32 + quad * 8];
      acc[nt] = __builtin_amdgcn_mfma_f32_16x16x32_bf16(af0, b0, acc[nt], 0, 0, 0);
      acc[nt] = __builtin_amdgcn_mfma_f32_16x16x32_bf16(af1, b1, acc[nt], 0, 0, 0);
    }
  }
  int which = N0 >> 9;
  int head  = (N0 & 511) >> 6;
  if (which == 2) {
    // V: transpose 64x64 tile through LDS, store [bh][d][4096] coalesced
    __syncthreads();
#pragma unroll
    for (int nt = 0; nt < 4; ++nt) {
      int d = nt * 16 + m16;
      float bias = bqkv[N0 + d];
#pragma unroll
      for (int r = 0; r < 4; ++r)
        At[d][w * 16 + quad * 4 + r] = f2b(acc[nt][r] + bias);
    }
    __syncthreads();
    int bb = M0 >> 12, p0 = M0 & 4095;
    unsigned short* dst = vo + ((size_t)(bb * 8 + head) * 64) * 4096;
#pragma unroll
    for (int pp = 0; pp < 2; ++pp) {
      int f = (pp * 256 + tid) * 8;
      int d = f >> 6, pl = f & 63;
      *(uint4*)(dst + (size_t)d * 4096 + p0 + pl) = *(uint4*)&At[d][pl];
    }
  } else if (which == 1) {
    // K: repack to frag-major Kp. Stage [key_local][d] in LDS, read back in
    // frag order, store lane-contiguous 1 KB chunks.
    __syncthreads();
#pragma unroll
    for (int nt = 0; nt < 4; ++nt) {
      float bias = bqkv[N0 + nt * 16 + m16];
#pragma unroll
      for (int r = 0; r < 4; ++r)
        At[w * 16 + quad * 4 + r][nt * 16 + m16] = f2b(acc[nt][r] + bias);
    }
    __syncthreads();
    int bb = M0 >> 12, p = M0 & 4095;
    int kb = p >> 7, halfblk = (p >> 6) & 1;
    int ig = halfblk * 4 + w;             // ig = nt_g*2+hh, nt_g=halfblk*2+(w>>1), hh=w&1
    int ntl = w >> 1, hh = w & 1;
    int row = ntl * 32 + hh * 4 + ((m16 >> 2) << 3) + (m16 & 3);  // local key row
    size_t dstb = (((size_t)(bb * 8 + head) * 32 + kb) * 8 + ig) * 1024;
#pragma unroll
    for (int pp = 0; pp < 2; ++pp)
      *(uint4*)(Kp + dstb + pp * 512 + l * 8) = *(uint4*)&At[row][pp * 32 + quad * 8];
  } else {
    // Q: row-major per-head
#pragma unroll
    for (int nt = 0; nt < 4; ++nt) {
      int n = N0 + nt * 16 + m16;
      float bias = bqkv[n];
      int d = n & 63;
#pragma unroll
      for (int r = 0; r < 4; ++r) {
        int m = M0 + w * 16 + quad * 4 + r;   // pixel 0..8191
        int b = m >> 12, pp2 = m & 4095;
        qo[(((size_t)(b * 8 + head) * 4096 + pp2) << 6) + d] = f2b(acc[nt][r] + bias);
      }
    }
  }
}

// ---------------- 5. flash attention: double-buffered K/V DMA, 64-key rounds ----------------
// R7/R8: all staging via global_load_lds (K dedup + V pre-swizzled src) ->
// 98 us, MfmaUtil 34%, VALU 49%. Cycle audit: ~1280 cyc/round all-wave dead
// time = the DMA drain. Old structure exposed the full L2 round trip every
// round: barrier -> issue DMA -> barrier(vmcnt 0) -> compute.
// R9: double-buffer. KVBLK 128->64 so K(8K)+V(8K) x2 = 32 KB/block keeps 4
// blocks/CU. Per round: issue DMA for kt+1 into buf^1 BEFORE compute on buf;
// the round-end barrier drains loads issued a full compute phase ago ->
// latency hidden. One barrier per 64-key round (64 total = same as 2x32).
// No vmcnt-order hazard (R3's failure): DMA is the ONLY vmem in the loop.
// Frag-major Kp is contiguous per 64-key round: src = Kp + bh*256K + kt*4K.
// V swizzle re-derived for 64-wide rows: LDS[d][cb] = V[d][cb^(d&7)] (src
// side, vgoff) ; PV reads cb' = (nt*4+quad)^(m16&7) -> 8 lanes/16B-group =
// 2/bank = free. defer-max (T13) kept.
__global__ __launch_bounds__(256, 4) void attn(
    const unsigned short* __restrict__ q, const unsigned short* __restrict__ Kp,
    const unsigned short* __restrict__ vt,
    unsigned short* __restrict__ ob) {
  int qt = blockIdx.x;           // 0..63  (64-query tile)
  int bh = blockIdx.y;           // 0..15
  __shared__ unsigned short Klds[2][4096];  // 8 KB per buf, frag-major
  __shared__ unsigned short Vt[2][64][64];  // 8 KB per buf, [d][key16B-swz]
  int tid = threadIdx.x, w = tid >> 6, l = tid & 63;
  int quad = l >> 4, m16 = l & 15;
  const size_t vbase = (size_t)bh * HWN * DHD;
  const unsigned short* kbase = Kp + (size_t)bh * 262144;

  // V source offsets, pre-swizzled (kt-invariant). Chunk c=w*2+i covers LDS
  // rows 8c..8c+7; lane l -> row = 8c+(l>>3), col block cb = l&7; source col
  // block = cb ^ (row&7)  =>  LDS[row][cb] = V[row][cb^(row&7)].
  int vgoff[2];
#pragma unroll
  for (int i = 0; i < 2; ++i) {
    int c = w * 2 + i;
    int row = 8 * c + (l >> 3);
    int cb = l & 7;
    vgoff[i] = row * 4096 + ((cb ^ (row & 7)) << 3);
  }

  bf16x8 qf0, qf1;   // Q[qrow][quad*8+j] -> B-frag of K=32 mfma
  {
    int qrow = qt * 64 + w * 16 + m16;
    const unsigned short* qp = q + vbase + (size_t)qrow * 64 + quad * 8;
    qf0 = *(const bf16x8*)qp;
    qf1 = *(const bf16x8*)(qp + 32);
  }
  bf16x8 ones;
#pragma unroll
  for (int z = 0; z < 8; ++z) ones[z] = (short)0x3F80;   // 1.0 bf16

  floatx4 accO[4] = {};   // O[q=quad*4+i][d=dt*16+m16]
  floatx4 accL = {};      // l[q=quad*4+i]
  float mrow = -1e30f;    // per-lane running max, query = m16

  // prologue: DMA round 0 into buf 0, drain at barrier
#pragma unroll
  for (int i = 0; i < 2; ++i) {
    int c = w * 2 + i;
    __builtin_amdgcn_global_load_lds(
        (const __attribute__((address_space(1))) unsigned int*)(kbase + c * 512 + l * 8),
        (__attribute__((address_space(3))) unsigned int*)(&Klds[0][0] + c * 512),
        16, 0, 0);
    __builtin_amdgcn_global_load_lds(
        (const __attribute__((address_space(1))) unsigned int*)(vt + vbase + vgoff[i]),
        (__attribute__((address_space(3))) unsigned int*)(&Vt[0][0][0] + c * 512),
        16, 0, 0);
  }
  __syncthreads();

  for (int kt = 0; kt < 64; ++kt) {
    int cur = kt & 1;
    // issue-early: DMA round kt+1 into the other buffer; in flight under
    // this round's compute, drained by the round-end barrier.
    if (kt < 63) {
      const unsigned short* kpn = kbase + (kt + 1) * 4096;
      const unsigned short* vpn = vt + vbase + (kt + 1) * 64;
      unsigned short* kd = &Klds[cur ^ 1][0];
      unsigned short* vd = &Vt[cur ^ 1][0][0];
#pragma unroll
      for (int i = 0; i < 2; ++i) {
        int c = w * 2 + i;
        __builtin_amdgcn_global_load_lds(
            (const __attribute__((address_space(1))) unsigned int*)(kpn + c * 512 + l * 8),
            (__attribute__((address_space(3))) unsigned int*)(kd + c * 512),
            16, 0, 0);
        __builtin_amdgcn_global_load_lds(
            (const __attribute__((address_space(1))) unsigned int*)(vpn + vgoff[i]),
            (__attribute__((address_space(3))) unsigned int*)(vd + c * 512),
            16, 0, 0);
      }
    }
    // S^T = K * Q^T from LDS frags. Key mapping (permuted within the round):
    // s[ig][i] = S[q=m16][key = kt*64 + (ig>>1)*32 + quad*8 + (ig&1)*4 + i]
    const unsigned short* kl = &Klds[cur][0] + l * 8;
    floatx4 s[4];
#pragma unroll
    for (int ig = 0; ig < 4; ++ig) {
      bf16x8 kf0 = *(const bf16x8*)(kl + ig * 1024);
      bf16x8 kf1 = *(const bf16x8*)(kl + ig * 1024 + 512);
      floatx4 z = {};
      z = __builtin_amdgcn_mfma_f32_16x16x32_bf16(kf0, qf0, z, 0, 0, 0);
      s[ig] = __builtin_amdgcn_mfma_f32_16x16x32_bf16(kf1, qf1, z, 0, 0, 0);
    }
    // online softmax: reduce across quads only (xor 16, 32)
    float mx = s[0][0];
#pragma unroll
    for (int ig = 0; ig < 4; ++ig)
#pragma unroll
      for (int i = 0; i < 4; ++i) mx = fmaxf(mx, s[ig][i]);
    mx = fmaxf(mx, __shfl_xor(mx, 16));
    mx = fmaxf(mx, __shfl_xor(mx, 32));
    // defer-max: only rescale when the max grows by > 8 (log2 domain);
    // otherwise keep mrow, P bounded by 2^8 = 256 (bf16-safe).
    bool grew = mx > mrow + 8.0f;
    if (__ballot(grew)) {
      float mnew = grew ? mx : mrow;
      float alpha = fast_exp2(mrow - mnew);   // 1.0 for lanes that didn't grow
      float al0 = __shfl(alpha, quad * 4 + 0);
      float al1 = __shfl(alpha, quad * 4 + 1);
      float al2 = __shfl(alpha, quad * 4 + 2);
      float al3 = __shfl(alpha, quad * 4 + 3);
#pragma unroll
      for (int dt = 0; dt < 4; ++dt) {
        accO[dt][0] *= al0; accO[dt][1] *= al1;
        accO[dt][2] *= al2; accO[dt][3] *= al3;
      }
      accL[0] *= al0; accL[1] *= al1; accL[2] *= al2; accL[3] *= al3;
      mrow = mnew;
    }
#pragma unroll
    for (int ig = 0; ig < 4; ++ig)
#pragma unroll
      for (int i = 0; i < 4; ++i)
        s[ig][i] = fast_exp2(s[ig][i] - mrow);
    // P -> bf16 A-frags (K=32): element j = hh*4+i from s[nt*2+hh][i]
    bf16x8 pf[2];
#pragma unroll
    for (int nt = 0; nt < 2; ++nt) {
      union { unsigned u[4]; bf16x8 v; } pu;
      pu.u[0] = pack_bf16_trunc(s[nt * 2][0],     s[nt * 2][1]);
      pu.u[1] = pack_bf16_trunc(s[nt * 2][2],     s[nt * 2][3]);
      pu.u[2] = pack_bf16_trunc(s[nt * 2 + 1][0], s[nt * 2 + 1][1]);
      pu.u[3] = pack_bf16_trunc(s[nt * 2 + 1][2], s[nt * 2 + 1][3]);
      pf[nt] = pu.v;
    }
    // O += P*V (K=32): B-frag = Vt[cur][d=dt*16+m16][swizzled key block]
#pragma unroll
    for (int dt = 0; dt < 4; ++dt) {
#pragma unroll
      for (int nt = 0; nt < 2; ++nt) {
        bf16x8 vf = *(const bf16x8*)&Vt[cur][dt * 16 + m16][((nt * 4 + quad) ^ (m16 & 7)) << 3];
        accO[dt] = __builtin_amdgcn_mfma_f32_16x16x32_bf16(pf[nt], vf, accO[dt], 0, 0, 0);
      }
    }
#pragma unroll
    for (int nt = 0; nt < 2; ++nt)
      accL = __builtin_amdgcn_mfma_f32_16x16x32_bf16(pf[nt], ones, accL, 0, 0, 0);
    __syncthreads();   // drains DMA for kt+1 + all waves done with buf[cur]
  }
  // ---- epilogue: normalized bf16 output straight to ob[(b*4096+q)*512+h*64+d] ----
  int b = bh >> 3, h = bh & 7;
  float li0 = 1.f / accL[0];
  float li1 = 1.f / accL[1];
  float li2 = 1.f / accL[2];
  float li3 = 1.f / accL[3];
  int qrow = qt * 64 + w * 16 + quad * 4;
  unsigned short* op = ob + ((size_t)(b * 4096 + qrow)) * 512 + h * 64;
#pragma unroll
  for (int dt = 0; dt < 4; ++dt) {
    int d = dt * 16 + m16;
    op[d]         = f2b(accO[dt][0] * li0);
    op[512 + d]   = f2b(accO[dt][1] * li1);
    op[1024 + d]  = f2b(accO[dt][2] * li2);
    op[1536 + d]  = f2b(accO[dt][3] * li3);
  }
}

// ---------------- 6. out-proj + bias + residual, coalesced fp32 store ----------------
__global__ __launch_bounds__(256) void gemm_out(
    const unsigned short* __restrict__ o, const unsigned short* __restrict__ Wp,
    const float* __restrict__ bp, const float* __restrict__ x,
    float* __restrict__ out) {
  int C0 = blockIdx.x * 64, P0 = blockIdx.y * 64, b = blockIdx.z;
  __shared__ unsigned short At[64][72];   // Wp rows (channel)
  __shared__ unsigned short Bt[64][72];   // o rows (pixel)
  int tid = threadIdx.x, w = tid >> 6, l = tid & 63;
  int quad = l >> 4, m16 = l & 15;
  floatx4 acc[4] = {};
  for (int k0 = 0; k0 < 512; k0 += 64) {
    __syncthreads();
#pragma unroll
    for (int pp = 0; pp < 2; ++pp) {
      int f = (pp * 256 + tid) * 8;
      int r = f >> 6, c = f & 63;
      *(uint4*)&At[r][c] = *(const uint4*)(Wp + (size_t)(C0 + r) * 512 + k0 + c);
      *(uint4*)&Bt[r][c] = *(const uint4*)(o + ((size_t)(b * 4096 + P0 + r)) * 512 + k0 + c);
    }
    __syncthreads();
    bf16x8 af0 = *(const bf16x8*)&At[w * 16 + m16][quad * 8];
    bf16x8 af1 = *(const bf16x8*)&At[w * 16 + m16][32 + quad * 8];
#pragma unroll
    for (int nt = 0; nt < 4; ++nt) {
      bf16x8 b0 = *(const bf16x8*)&Bt[nt * 16 + m16][quad * 8];
      bf16x8 b1 = *(const bf16x8*)&Bt[nt * 16 + m16][32 + quad * 8];
      acc[nt] = __builtin_amdgcn_mfma_f32_16x16x32_bf16(af0, b0, acc[nt], 0, 0, 0);
      acc[nt] = __builtin_amdgcn_mfma_f32_16x16x32_bf16(af1, b1, acc[nt], 0, 0, 0);
    }
  }
#pragma unroll
  for (int r = 0; r < 4; ++r) {
    int c = C0 + w * 16 + quad * 4 + r;
    float bias = bp[c];
#pragma unroll
    for (int nt = 0; nt < 4; ++nt) {
      int p = P0 + nt * 16 + m16;
      size_t idx = ((size_t)(b * 512 + c)) * 4096 + p;
      out[idx] = acc[nt][r] + bias + x[idx];
    }
  }
}

extern "C" void kernel_launch(void* const* d_in, const int* in_sizes, int n_in,
                              void* d_out, int out_size, void* d_ws, size_t ws_size,
                              hipStream_t stream) {
  const float* x   = (const float*)d_in[0];
  const float* gnw = (const float*)d_in[1];
  const float* gnb = (const float*)d_in[2];
  const float* wq  = (const float*)d_in[3];
  const float* bq  = (const float*)d_in[4];
  const float* wk  = (const float*)d_in[5];
  const float* bk  = (const float*)d_in[6];
  const float* wv  = (const float*)d_in[7];
  const float* bv  = (const float*)d_in[8];
  const float* wp  = (const float*)d_in[9];
  const float* bp  = (const float*)d_in[10];
  float* out = (float*)d_out;

  char* ws = (char*)d_ws;
  float* stat          = (float*)ws;          ws += 1024;
  float* bqkv          = (float*)ws;          ws += 8192;
  unsigned short* Wqkv = (unsigned short*)ws; ws += (size_t)1536 * 512 * 2;
  unsigned short* Wp   = (unsigned short*)ws; ws += (size_t)512 * 512 * 2;
  unsigned short* t    = (unsigned short*)ws; ws += (size_t)8192 * 512 * 2;
  unsigned short* qb   = (unsigned short*)ws; ws += (size_t)8192 * 512 * 2;
  unsigned short* Kp   = (unsigned short*)ws; ws += (size_t)8192 * 512 * 2;  // frag-major K
  unsigned short* vb   = (unsigned short*)ws; ws += (size_t)8192 * 512 * 2;  // [16][64][4096]
  unsigned short* ob   = (unsigned short*)ws; ws += (size_t)8192 * 512 * 2;

  hipMemsetAsync(stat, 0, 512, stream);
  prep_gn<<<4615, 256, 0, stream>>>(x, stat, wq, wk, wv, wp, bq, bk, bv, Wqkv, Wp, bqkv);
  gn_apply<<<1024, 256, 0, stream>>>(x, stat, gnw, gnb, t);
  dim3 g1(128, 24);
  gemm_qkv<<<g1, 256, 0, stream>>>(t, Wqkv, bqkv, qb, Kp, vb);
  dim3 g2(64, 16);
  attn<<<g2, 256, 0, stream>>>(qb, Kp, vb, ob);
  dim3 g3(8, 64, 2);
  gemm_out<<<g3, 256, 0, stream>>>(ob, Wp, bp, x, out);
}

// Round 10
// 230.809 us; speedup vs baseline: 1.0288x; 1.0288x over previous
//
#include <hip/hip_runtime.h>

// ---- problem constants ----
#define HWN 4096
#define CCH 512
#define NHEAD 8
#define DHD 64
#define NBATCH 2
#define QK_SCALE 0.35355339059327373f   // 64^-0.25
#define LOG2E    1.4426950408889634f

using floatx4 = __attribute__((ext_vector_type(4))) float;
using bf16x8  = __attribute__((ext_vector_type(8))) short;
using bf16x4  = __attribute__((ext_vector_type(4))) short;

__device__ __forceinline__ unsigned short f2b(float f) {
  union { float f; unsigned u; } x; x.f = f;
  unsigned r = x.u + 0x7FFFu + ((x.u >> 16) & 1u);
  return (unsigned short)(r >> 16);
}

__device__ __forceinline__ float b2f(unsigned short u) {
  union { unsigned u; float f; } x; x.u = ((unsigned)u) << 16;
  return x.f;
}

__device__ __forceinline__ float fast_exp2(float x) {
#if __has_builtin(__builtin_amdgcn_exp2f)
  return __builtin_amdgcn_exp2f(x);
#else
  return __expf(x * 0.69314718056f);
#endif
}

// pack bf16(lo),bf16(hi) from two floats in ONE v_perm_b32 (truncating round)
__device__ __forceinline__ unsigned pack_bf16_trunc(float lo, float hi) {
  return __builtin_amdgcn_perm(__float_as_uint(hi), __float_as_uint(lo), 0x07060302u);
}

// ------- 1+2 merged. blocks [0,4103): weight prep; [4103,4615): GN stats -------
__global__ __launch_bounds__(256) void prep_gn(
    const float* __restrict__ x, float* __restrict__ stat,
    const float* __restrict__ wq, const float* __restrict__ wk,
    const float* __restrict__ wv, const float* __restrict__ wp,
    const float* __restrict__ bq, const float* __restrict__ bk,
    const float* __restrict__ bv,
    unsigned short* __restrict__ Wqkv, unsigned short* __restrict__ Wp,
    float* __restrict__ bqkv) {
  if (blockIdx.x >= 4103) {
    // GroupNorm partial sums: 512 virtual blocks = (64 groups x 8 parts)
    int idx = blockIdx.x - 4103;
    int bg = idx & 63, part = idx >> 6;
    const float4* p = (const float4*)(x + (size_t)bg * 65536) + part * 2048;
    float s = 0.f, ss = 0.f;
    for (int i = threadIdx.x; i < 2048; i += 256) {
      float4 v = p[i];
      s  += v.x + v.y + v.z + v.w;
      ss += v.x*v.x + v.y*v.y + v.z*v.z + v.w*v.w;
    }
    for (int off = 32; off; off >>= 1) {
      s  += __shfl_xor(s, off);
      ss += __shfl_xor(ss, off);
    }
    __shared__ float red[8];
    int w = threadIdx.x >> 6;
    if ((threadIdx.x & 63) == 0) { red[w] = s; red[4 + w] = ss; }
    __syncthreads();
    if (threadIdx.x == 0) {
      float S  = red[0] + red[1] + red[2] + red[3];
      float SS = red[4] + red[5] + red[6] + red[7];
      atomicAdd(&stat[bg], S);
      atomicAdd(&stat[64 + bg], SS);
    }
    return;
  }
  // weight prep: fp32 -> bf16, fold SCALE (and log2e into q)
  int i = blockIdx.x * 256 + threadIdx.x;
  if (i < 786432) {                       // Wqkv: rows 0-511 q, 512-1023 k, 1024-1535 v
    int row = i >> 9;
    float v;
    if (row < 512)       v = wq[i] * (QK_SCALE * LOG2E);
    else if (row < 1024) v = wk[i - 262144] * QK_SCALE;
    else                 v = wv[i - 524288];
    Wqkv[i] = f2b(v);
  } else if (i < 1048576) {
    Wp[i - 786432] = f2b(wp[i - 786432]);
  } else if (i < 1050112) {
    int j = i - 1048576;
    float v = (j < 512) ? bq[j] * (QK_SCALE * LOG2E)
            : (j < 1024) ? bk[j - 512] * QK_SCALE
            : bv[j - 1024];
    bqkv[j] = v;
  }
}

// ---------------- 3. normalize + transpose to t[(b*4096+p)*512 + c] bf16 ----------------
__global__ __launch_bounds__(256) void gn_apply(
    const float* __restrict__ x, const float* __restrict__ stat,
    const float* __restrict__ gnw, const float* __restrict__ gnb,
    unsigned short* __restrict__ t) {
  int pt = blockIdx.x & 63;
  int ct = (blockIdx.x >> 6) & 7;
  int b  = blockIdx.x >> 9;
  int c0 = ct * 64, p0 = pt * 64;
  __shared__ float tile[64][68];          // pad 68: bank shift 4/row, float4-aligned
  int tid = threadIdx.x;
  for (int pp = 0; pp < 4; ++pp) {
    int f = (pp * 256 + tid) * 4;
    int cl = f >> 6, pl = f & 63;
    int c = c0 + cl;
    float4 v = *(const float4*)(x + ((size_t)(b * 512 + c)) * 4096 + p0 + pl);
    int g = c >> 4;
    float S    = stat[b * 32 + g];
    float SS   = stat[64 + b * 32 + g];
    float mean = S * (1.f / 65536.f);
    float var  = SS * (1.f / 65536.f) - mean * mean;
    float rstd = rsqrtf(var + 1e-5f);
    float w  = gnw[c] * rstd;
    float bb = gnb[c] - mean * w;
    tile[cl][pl + 0] = v.x * w + bb;
    tile[cl][pl + 1] = v.y * w + bb;
    tile[cl][pl + 2] = v.z * w + bb;
    tile[cl][pl + 3] = v.w * w + bb;
  }
  __syncthreads();
  for (int pp = 0; pp < 2; ++pp) {
    int f = (pp * 256 + tid) * 8;
    int pl = f >> 6, cl = f & 63;
    unsigned short u[8];
#pragma unroll
    for (int j = 0; j < 8; ++j) u[j] = f2b(tile[cl + j][pl]);
    *(uint4*)(t + ((size_t)(b * 4096 + p0 + pl)) * 512 + c0 + cl) = *(uint4*)u;
  }
}

// ---------------- 4. QKV GEMM ----------------
// Main-loop staging via global_load_lds (R7/R8-proven mechanism): unpadded
// [64][64] At/Bt, source col-block XOR-swizzled by row&7, frag reads apply
// the same XOR -> 2 lanes/bank (free). Epilogues untouched (they rewrite At
// after a barrier with their own consistent indexing).
// q: [(bh*4096+p)*64+d] bf16 ; v: TRANSPOSED [bh][d][4096] bf16 ;
// K: FRAG-MAJOR Kp[bh][kb(32)][ig(8)][half(2)][lane(64)x8] bf16 — each 1 KB
// chunk is exactly one wave-wide A-frag load for attn (lane-contiguous 16 B).
__global__ __launch_bounds__(256) void gemm_qkv(
    const unsigned short* __restrict__ t, const unsigned short* __restrict__ Wqkv,
    const float* __restrict__ bqkv,
    unsigned short* __restrict__ qo, unsigned short* __restrict__ Kp,
    unsigned short* __restrict__ vo) {
  int M0 = blockIdx.x * 64;   // pixel 0..8128
  int N0 = blockIdx.y * 64;   // outch 0..1472
  __shared__ unsigned short At[64][64];
  __shared__ unsigned short Bt[64][64];
  int tid = threadIdx.x, w = tid >> 6, l = tid & 63;
  int quad = l >> 4, m16 = l & 15;
  // per-lane DMA source offsets (k0-invariant part). Chunk c = w*2+i covers
  // LDS rows 8c..8c+7; lane l -> row = 8c+(l>>3), col-block cb = l&7; source
  // col-block = cb ^ (row&7)  =>  LDS[row][cb] = SRC[row][cb^(row&7)].
  int offA[2], offB[2];
#pragma unroll
  for (int i = 0; i < 2; ++i) {
    int c = w * 2 + i;
    int row = 8 * c + (l >> 3);
    int cbs = ((l & 7) ^ (row & 7)) << 3;
    offA[i] = (M0 + row) * 512 + cbs;
    offB[i] = (N0 + row) * 512 + cbs;
  }
  int swa = m16 & 7;
  floatx4 acc[4] = {};
  for (int k0 = 0; k0 < 512; k0 += 64) {
    __syncthreads();
#pragma unroll
    for (int i = 0; i < 2; ++i) {
      int c = w * 2 + i;
      __builtin_amdgcn_global_load_lds(
          (const __attribute__((address_space(1))) unsigned int*)(t + offA[i] + k0),
          (__attribute__((address_space(3))) unsigned int*)(&At[0][0] + c * 512),
          16, 0, 0);
      __builtin_amdgcn_global_load_lds(
          (const __attribute__((address_space(1))) unsigned int*)(Wqkv + offB[i] + k0),
          (__attribute__((address_space(3))) unsigned int*)(&Bt[0][0] + c * 512),
          16, 0, 0);
    }
    __syncthreads();
    bf16x8 af0 = *(const bf16x8*)&At[w * 16 + m16][(quad ^ swa) << 3];
    bf16x8 af1 = *(const bf16x8*)&At[w * 16 + m16][((4 + quad) ^ swa) << 3];
#pragma unroll
    for (int nt = 0; nt < 4; ++nt) {
      bf16x8 b0 = *(const bf16x8*)&Bt[nt * 16 + m16][(quad ^ swa) << 3];
      bf16x8 b1 = *(const bf16x8*)&Bt[nt * 16 + m16][((4 + quad) ^ swa) << 3];
      acc[nt] = __builtin_amdgcn_mfma_f32_16x16x32_bf16(af0, b0, acc[nt], 0, 0, 0);
      acc[nt] = __builtin_amdgcn_mfma_f32_16x16x32_bf16(af1, b1, acc[nt], 0, 0, 0);
    }
  }
  int which = N0 >> 9;
  int head  = (N0 & 511) >> 6;
  if (which == 2) {
    // V: transpose 64x64 tile through LDS, store [bh][d][4096] coalesced
    __syncthreads();
#pragma unroll
    for (int nt = 0; nt < 4; ++nt) {
      int d = nt * 16 + m16;
      float bias = bqkv[N0 + d];
#pragma unroll
      for (int r = 0; r < 4; ++r)
        At[d][w * 16 + quad * 4 + r] = f2b(acc[nt][r] + bias);
    }
    __syncthreads();
    int bb = M0 >> 12, p0 = M0 & 4095;
    unsigned short* dst = vo + ((size_t)(bb * 8 + head) * 64) * 4096;
#pragma unroll
    for (int pp = 0; pp < 2; ++pp) {
      int f = (pp * 256 + tid) * 8;
      int d = f >> 6, pl = f & 63;
      *(uint4*)(dst + (size_t)d * 4096 + p0 + pl) = *(uint4*)&At[d][pl];
    }
  } else if (which == 1) {
    // K: repack to frag-major Kp. Stage [key_local][d] in LDS, read back in
    // frag order, store lane-contiguous 1 KB chunks.
    __syncthreads();
#pragma unroll
    for (int nt = 0; nt < 4; ++nt) {
      float bias = bqkv[N0 + nt * 16 + m16];
#pragma unroll
      for (int r = 0; r < 4; ++r)
        At[w * 16 + quad * 4 + r][nt * 16 + m16] = f2b(acc[nt][r] + bias);
    }
    __syncthreads();
    int bb = M0 >> 12, p = M0 & 4095;
    int kb = p >> 7, halfblk = (p >> 6) & 1;
    int ig = halfblk * 4 + w;             // ig = nt_g*2+hh, nt_g=halfblk*2+(w>>1), hh=w&1
    int ntl = w >> 1, hh = w & 1;
    int row = ntl * 32 + hh * 4 + ((m16 >> 2) << 3) + (m16 & 3);  // local key row
    size_t dstb = (((size_t)(bb * 8 + head) * 32 + kb) * 8 + ig) * 1024;
#pragma unroll
    for (int pp = 0; pp < 2; ++pp)
      *(uint4*)(Kp + dstb + pp * 512 + l * 8) = *(uint4*)&At[row][pp * 32 + quad * 8];
  } else {
    // Q: row-major per-head
#pragma unroll
    for (int nt = 0; nt < 4; ++nt) {
      int n = N0 + nt * 16 + m16;
      float bias = bqkv[n];
      int d = n & 63;
#pragma unroll
      for (int r = 0; r < 4; ++r) {
        int m = M0 + w * 16 + quad * 4 + r;   // pixel 0..8191
        int b = m >> 12, pp2 = m & 4095;
        qo[(((size_t)(b * 8 + head) * 4096 + pp2) << 6) + d] = f2b(acc[nt][r] + bias);
      }
    }
  }
}

// ---------------- 5. flash attention: K AND V staged via LDS DMA (R8) ----------------
// R9 lesson: KVBLK 64 + dbuf regressed (+10.6 us) — doubled per-round serial
// overhead (shuffles/ballot/loop) outweighs hiding the drain. KVBLK=128
// single-buffer (R8, 98.4 us) is the operating point.
// This version = R8 exactly, plus a max-TREE (depth 5, v_max3-fusable)
// replacing the 31-deep serial fmax chain that sat on the critical path
// before all 32 exp2s each round.
__global__ __launch_bounds__(256, 4) void attn(
    const unsigned short* __restrict__ q, const unsigned short* __restrict__ Kp,
    const unsigned short* __restrict__ vt,
    unsigned short* __restrict__ ob) {
  int qt = blockIdx.x;           // 0..63  (64-query tile)
  int bh = blockIdx.y;           // 0..15
  __shared__ unsigned short Klds[8192];     // 16 KB frag-major K block
  __shared__ unsigned short Vt[64][128];    // 16 KB [d][key16B-swz]
  int tid = threadIdx.x, w = tid >> 6, l = tid & 63;
  int quad = l >> 4, m16 = l & 15;
  const size_t vbase = (size_t)bh * HWN * DHD;

  // per-lane pre-swizzled V source offsets (kt-invariant). Chunk c=w*4+i is
  // LDS rows 4c..4c+3; lane l lands at row=4c+(l>>4), col block cb=l&15, so
  // source col block = cb ^ (row&15)  =>  LDS[row][cb] = V[row][cb^(row&15)].
  int goff[4];
#pragma unroll
  for (int i = 0; i < 4; ++i) {
    int c = w * 4 + i;
    int row = 4 * c + (l >> 4);
    int cbl = l & 15;
    goff[i] = row * 4096 + ((cbl ^ (row & 15)) << 3);
  }

  bf16x8 qf0, qf1;   // Q[qrow][quad*8+j] -> B-frag of K=32 mfma
  {
    int qrow = qt * 64 + w * 16 + m16;
    const unsigned short* qp = q + vbase + (size_t)qrow * 64 + quad * 8;
    qf0 = *(const bf16x8*)qp;
    qf1 = *(const bf16x8*)(qp + 32);
  }
  bf16x8 ones;
#pragma unroll
  for (int z = 0; z < 8; ++z) ones[z] = (short)0x3F80;   // 1.0 bf16

  floatx4 accO[4] = {};   // O[q=quad*4+i][d=dt*16+m16]
  floatx4 accL = {};      // l[q=quad*4+i]
  float mrow = -1e30f;    // per-lane running max, query = m16

  for (int kt = 0; kt < 32; ++kt) {
    __syncthreads();      // all waves done reading Klds/Vt of round kt-1
    // K block: 16 x 1KB chunks, 4 DMA per wave; frag-major source is already
    // lane-contiguous (lands exactly where QK^T reads: ig*1024(+512) + l*8).
    const unsigned short* kpb = Kp + (((size_t)bh * 32 + kt) * 8) * 1024;
    const unsigned short* vtile = vt + vbase + kt * 128;
#pragma unroll
    for (int i = 0; i < 4; ++i) {
      int c = w * 4 + i;
      __builtin_amdgcn_global_load_lds(
          (const __attribute__((address_space(1))) unsigned int*)(kpb + c * 512 + l * 8),
          (__attribute__((address_space(3))) unsigned int*)(Klds + c * 512),
          16, 0, 0);
      __builtin_amdgcn_global_load_lds(
          (const __attribute__((address_space(1))) unsigned int*)(vtile + goff[i]),
          (__attribute__((address_space(3))) unsigned int*)(&Vt[0][0] + c * 512),
          16, 0, 0);
    }
    __syncthreads();      // vmcnt(0) drain: K+V landed, ready for all waves
    // S^T = K * Q^T, K A-frags from LDS (permuted-key semantics:
    // s[ig][i] = S[q=m16][key = kt*128 + (ig>>1)*32 + quad*8 + (ig&1)*4 + i])
    const unsigned short* kl = Klds + l * 8;
    floatx4 s[8];
#pragma unroll
    for (int ig = 0; ig < 8; ++ig) {
      bf16x8 kf0 = *(const bf16x8*)(kl + ig * 1024);
      bf16x8 kf1 = *(const bf16x8*)(kl + ig * 1024 + 512);
      floatx4 z = {};
      z = __builtin_amdgcn_mfma_f32_16x16x32_bf16(kf0, qf0, z, 0, 0, 0);
      s[ig] = __builtin_amdgcn_mfma_f32_16x16x32_bf16(kf1, qf1, z, 0, 0, 0);
    }
    // row max: depth-5 tree (v_max3-fusable), not a 31-deep serial chain
    float g0 = fmaxf(fmaxf(s[0][0], s[0][1]), fmaxf(s[0][2], s[0][3]));
    float g1 = fmaxf(fmaxf(s[1][0], s[1][1]), fmaxf(s[1][2], s[1][3]));
    float g2 = fmaxf(fmaxf(s[2][0], s[2][1]), fmaxf(s[2][2], s[2][3]));
    float g3 = fmaxf(fmaxf(s[3][0], s[3][1]), fmaxf(s[3][2], s[3][3]));
    float g4 = fmaxf(fmaxf(s[4][0], s[4][1]), fmaxf(s[4][2], s[4][3]));
    float g5 = fmaxf(fmaxf(s[5][0], s[5][1]), fmaxf(s[5][2], s[5][3]));
    float g6 = fmaxf(fmaxf(s[6][0], s[6][1]), fmaxf(s[6][2], s[6][3]));
    float g7 = fmaxf(fmaxf(s[7][0], s[7][1]), fmaxf(s[7][2], s[7][3]));
    float mx = fmaxf(fmaxf(fmaxf(g0, g1), fmaxf(g2, g3)),
                     fmaxf(fmaxf(g4, g5), fmaxf(g6, g7)));
    mx = fmaxf(mx, __shfl_xor(mx, 16));
    mx = fmaxf(mx, __shfl_xor(mx, 32));
    // defer-max: only rescale when the max grows by > 8 (log2 domain);
    // otherwise keep mrow, P bounded by 2^8 = 256 (bf16-safe).
    bool grew = mx > mrow + 8.0f;
    if (__ballot(grew)) {
      float mnew = grew ? mx : mrow;
      float alpha = fast_exp2(mrow - mnew);   // 1.0 for lanes that didn't grow
      float al0 = __shfl(alpha, quad * 4 + 0);
      float al1 = __shfl(alpha, quad * 4 + 1);
      float al2 = __shfl(alpha, quad * 4 + 2);
      float al3 = __shfl(alpha, quad * 4 + 3);
#pragma unroll
      for (int dt = 0; dt < 4; ++dt) {
        accO[dt][0] *= al0; accO[dt][1] *= al1;
        accO[dt][2] *= al2; accO[dt][3] *= al3;
      }
      accL[0] *= al0; accL[1] *= al1; accL[2] *= al2; accL[3] *= al3;
      mrow = mnew;
    }
#pragma unroll
    for (int ig = 0; ig < 8; ++ig)
#pragma unroll
      for (int i = 0; i < 4; ++i)
        s[ig][i] = fast_exp2(s[ig][i] - mrow);
    // P -> bf16 A-frags (K=32): element j = hh*4+i from s[nt*2+hh][i]
    bf16x8 pf[4];
#pragma unroll
    for (int nt = 0; nt < 4; ++nt) {
      union { unsigned u[4]; bf16x8 v; } pu;
      pu.u[0] = pack_bf16_trunc(s[nt * 2][0],     s[nt * 2][1]);
      pu.u[1] = pack_bf16_trunc(s[nt * 2][2],     s[nt * 2][3]);
      pu.u[2] = pack_bf16_trunc(s[nt * 2 + 1][0], s[nt * 2 + 1][1]);
      pu.u[3] = pack_bf16_trunc(s[nt * 2 + 1][2], s[nt * 2 + 1][3]);
      pf[nt] = pu.v;
    }
    // O += P*V (K=32): B-frag = Vt[d=dt*16+m16][swizzled key block], 0-conflict
#pragma unroll
    for (int dt = 0; dt < 4; ++dt) {
#pragma unroll
      for (int nt = 0; nt < 4; ++nt) {
        bf16x8 vf = *(const bf16x8*)&Vt[dt * 16 + m16][((nt * 4 + quad) ^ m16) << 3];
        accO[dt] = __builtin_amdgcn_mfma_f32_16x16x32_bf16(pf[nt], vf, accO[dt], 0, 0, 0);
      }
    }
#pragma unroll
    for (int nt = 0; nt < 4; ++nt)
      accL = __builtin_amdgcn_mfma_f32_16x16x32_bf16(pf[nt], ones, accL, 0, 0, 0);
  }
  // ---- epilogue: normalized bf16 output straight to ob[(b*4096+q)*512+h*64+d] ----
  int b = bh >> 3, h = bh & 7;
  float li0 = 1.f / accL[0];
  float li1 = 1.f / accL[1];
  float li2 = 1.f / accL[2];
  float li3 = 1.f / accL[3];
  int qrow = qt * 64 + w * 16 + quad * 4;
  unsigned short* op = ob + ((size_t)(b * 4096 + qrow)) * 512 + h * 64;
#pragma unroll
  for (int dt = 0; dt < 4; ++dt) {
    int d = dt * 16 + m16;
    op[d]         = f2b(accO[dt][0] * li0);
    op[512 + d]   = f2b(accO[dt][1] * li1);
    op[1024 + d]  = f2b(accO[dt][2] * li2);
    op[1536 + d]  = f2b(accO[dt][3] * li3);
  }
}

// ---------------- 6. out-proj + bias + residual, coalesced fp32 store ----------------
// Same DMA-staged main loop as gemm_qkv.
__global__ __launch_bounds__(256) void gemm_out(
    const unsigned short* __restrict__ o, const unsigned short* __restrict__ Wp,
    const float* __restrict__ bp, const float* __restrict__ x,
    float* __restrict__ out) {
  int C0 = blockIdx.x * 64, P0 = blockIdx.y * 64, b = blockIdx.z;
  __shared__ unsigned short At[64][64];   // Wp rows (channel)
  __shared__ unsigned short Bt[64][64];   // o rows (pixel)
  int tid = threadIdx.x, w = tid >> 6, l = tid & 63;
  int quad = l >> 4, m16 = l & 15;
  int offA[2], offB[2];
#pragma unroll
  for (int i = 0; i < 2; ++i) {
    int c = w * 2 + i;
    int row = 8 * c + (l >> 3);
    int cbs = ((l & 7) ^ (row & 7)) << 3;
    offA[i] = (C0 + row) * 512 + cbs;
    offB[i] = (b * 4096 + P0 + row) * 512 + cbs;
  }
  int swa = m16 & 7;
  floatx4 acc[4] = {};
  for (int k0 = 0; k0 < 512; k0 += 64) {
    __syncthreads();
#pragma unroll
    for (int i = 0; i < 2; ++i) {
      int c = w * 2 + i;
      __builtin_amdgcn_global_load_lds(
          (const __attribute__((address_space(1))) unsigned int*)(Wp + offA[i] + k0),
          (__attribute__((address_space(3))) unsigned int*)(&At[0][0] + c * 512),
          16, 0, 0);
      __builtin_amdgcn_global_load_lds(
          (const __attribute__((address_space(1))) unsigned int*)(o + (size_t)offB[i] + k0),
          (__attribute__((address_space(3))) unsigned int*)(&Bt[0][0] + c * 512),
          16, 0, 0);
    }
    __syncthreads();
    bf16x8 af0 = *(const bf16x8*)&At[w * 16 + m16][(quad ^ swa) << 3];
    bf16x8 af1 = *(const bf16x8*)&At[w * 16 + m16][((4 + quad) ^ swa) << 3];
#pragma unroll
    for (int nt = 0; nt < 4; ++nt) {
      bf16x8 b0 = *(const bf16x8*)&Bt[nt * 16 + m16][(quad ^ swa) << 3];
      bf16x8 b1 = *(const bf16x8*)&Bt[nt * 16 + m16][((4 + quad) ^ swa) << 3];
      acc[nt] = __builtin_amdgcn_mfma_f32_16x16x32_bf16(af0, b0, acc[nt], 0, 0, 0);
      acc[nt] = __builtin_amdgcn_mfma_f32_16x16x32_bf16(af1, b1, acc[nt], 0, 0, 0);
    }
  }
#pragma unroll
  for (int r = 0; r < 4; ++r) {
    int c = C0 + w * 16 + quad * 4 + r;
    float bias = bp[c];
#pragma unroll
    for (int nt = 0; nt < 4; ++nt) {
      int p = P0 + nt * 16 + m16;
      size_t idx = ((size_t)(b * 512 + c)) * 4096 + p;
      out[idx] = acc[nt][r] + bias + x[idx];
    }
  }
}

extern "C" void kernel_launch(void* const* d_in, const int* in_sizes, int n_in,
                              void* d_out, int out_size, void* d_ws, size_t ws_size,
                              hipStream_t stream) {
  const float* x   = (const float*)d_in[0];
  const float* gnw = (const float*)d_in[1];
  const float* gnb = (const float*)d_in[2];
  const float* wq  = (const float*)d_in[3];
  const float* bq  = (const float*)d_in[4];
  const float* wk  = (const float*)d_in[5];
  const float* bk  = (const float*)d_in[6];
  const float* wv  = (const float*)d_in[7];
  const float* bv  = (const float*)d_in[8];
  const float* wp  = (const float*)d_in[9];
  const float* bp  = (const float*)d_in[10];
  float* out = (float*)d_out;

  char* ws = (char*)d_ws;
  float* stat          = (float*)ws;          ws += 1024;
  float* bqkv          = (float*)ws;          ws += 8192;
  unsigned short* Wqkv = (unsigned short*)ws; ws += (size_t)1536 * 512 * 2;
  unsigned short* Wp   = (unsigned short*)ws; ws += (size_t)512 * 512 * 2;
  unsigned short* t    = (unsigned short*)ws; ws += (size_t)8192 * 512 * 2;
  unsigned short* qb   = (unsigned short*)ws; ws += (size_t)8192 * 512 * 2;
  unsigned short* Kp   = (unsigned short*)ws; ws += (size_t)8192 * 512 * 2;  // frag-major K
  unsigned short* vb   = (unsigned short*)ws; ws += (size_t)8192 * 512 * 2;  // [16][64][4096]
  unsigned short* ob   = (unsigned short*)ws; ws += (size_t)8192 * 512 * 2;

  hipMemsetAsync(stat, 0, 512, stream);
  prep_gn<<<4615, 256, 0, stream>>>(x, stat, wq, wk, wv, wp, bq, bk, bv, Wqkv, Wp, bqkv);
  gn_apply<<<1024, 256, 0, stream>>>(x, stat, gnw, gnb, t);
  dim3 g1(128, 24);
  gemm_qkv<<<g1, 256, 0, stream>>>(t, Wqkv, bqkv, qb, Kp, vb);
  dim3 g2(64, 16);
  attn<<<g2, 256, 0, stream>>>(qb, Kp, vb, ob);
  dim3 g3(8, 64, 2);
  gemm_out<<<g3, 256, 0, stream>>>(ob, Wp, bp, x, out);
}

// Round 11
// 223.137 us; speedup vs baseline: 1.0642x; 1.0344x over previous
//
#include <hip/hip_runtime.h>

// ---- problem constants ----
#define HWN 4096
#define CCH 512
#define NHEAD 8
#define DHD 64
#define NBATCH 2
#define QK_SCALE 0.35355339059327373f   // 64^-0.25
#define LOG2E    1.4426950408889634f

using floatx4 = __attribute__((ext_vector_type(4))) float;
using bf16x8  = __attribute__((ext_vector_type(8))) short;
using bf16x4  = __attribute__((ext_vector_type(4))) short;

__device__ __forceinline__ unsigned short f2b(float f) {
  union { float f; unsigned u; } x; x.f = f;
  unsigned r = x.u + 0x7FFFu + ((x.u >> 16) & 1u);
  return (unsigned short)(r >> 16);
}

__device__ __forceinline__ float b2f(unsigned short u) {
  union { unsigned u; float f; } x; x.u = ((unsigned)u) << 16;
  return x.f;
}

__device__ __forceinline__ float fast_exp2(float x) {
#if __has_builtin(__builtin_amdgcn_exp2f)
  return __builtin_amdgcn_exp2f(x);
#else
  return __expf(x * 0.69314718056f);
#endif
}

// pack bf16(lo),bf16(hi) from two floats in ONE v_perm_b32 (truncating round)
__device__ __forceinline__ unsigned pack_bf16_trunc(float lo, float hi) {
  return __builtin_amdgcn_perm(__float_as_uint(hi), __float_as_uint(lo), 0x07060302u);
}

// ------- 1+2 merged. blocks [0,4103): weight prep; [4103,4615): GN stats -------
__global__ __launch_bounds__(256) void prep_gn(
    const float* __restrict__ x, float* __restrict__ stat,
    const float* __restrict__ wq, const float* __restrict__ wk,
    const float* __restrict__ wv, const float* __restrict__ wp,
    const float* __restrict__ bq, const float* __restrict__ bk,
    const float* __restrict__ bv,
    unsigned short* __restrict__ Wqkv, unsigned short* __restrict__ Wp,
    float* __restrict__ bqkv) {
  if (blockIdx.x >= 4103) {
    // GroupNorm partial sums: 512 virtual blocks = (64 groups x 8 parts)
    int idx = blockIdx.x - 4103;
    int bg = idx & 63, part = idx >> 6;
    const float4* p = (const float4*)(x + (size_t)bg * 65536) + part * 2048;
    float s = 0.f, ss = 0.f;
    for (int i = threadIdx.x; i < 2048; i += 256) {
      float4 v = p[i];
      s  += v.x + v.y + v.z + v.w;
      ss += v.x*v.x + v.y*v.y + v.z*v.z + v.w*v.w;
    }
    for (int off = 32; off; off >>= 1) {
      s  += __shfl_xor(s, off);
      ss += __shfl_xor(ss, off);
    }
    __shared__ float red[8];
    int w = threadIdx.x >> 6;
    if ((threadIdx.x & 63) == 0) { red[w] = s; red[4 + w] = ss; }
    __syncthreads();
    if (threadIdx.x == 0) {
      float S  = red[0] + red[1] + red[2] + red[3];
      float SS = red[4] + red[5] + red[6] + red[7];
      atomicAdd(&stat[bg], S);
      atomicAdd(&stat[64 + bg], SS);
    }
    return;
  }
  // weight prep: fp32 -> bf16, fold SCALE (and log2e into q)
  int i = blockIdx.x * 256 + threadIdx.x;
  if (i < 786432) {                       // Wqkv: rows 0-511 q, 512-1023 k, 1024-1535 v
    int row = i >> 9;
    float v;
    if (row < 512)       v = wq[i] * (QK_SCALE * LOG2E);
    else if (row < 1024) v = wk[i - 262144] * QK_SCALE;
    else                 v = wv[i - 524288];
    Wqkv[i] = f2b(v);
  } else if (i < 1048576) {
    Wp[i - 786432] = f2b(wp[i - 786432]);
  } else if (i < 1050112) {
    int j = i - 1048576;
    float v = (j < 512) ? bq[j] * (QK_SCALE * LOG2E)
            : (j < 1024) ? bk[j - 512] * QK_SCALE
            : bv[j - 1024];
    bqkv[j] = v;
  }
}

// ---------------- 3. normalize + transpose to t[(b*4096+p)*512 + c] bf16 ----------------
__global__ __launch_bounds__(256) void gn_apply(
    const float* __restrict__ x, const float* __restrict__ stat,
    const float* __restrict__ gnw, const float* __restrict__ gnb,
    unsigned short* __restrict__ t) {
  int pt = blockIdx.x & 63;
  int ct = (blockIdx.x >> 6) & 7;
  int b  = blockIdx.x >> 9;
  int c0 = ct * 64, p0 = pt * 64;
  __shared__ float tile[64][68];          // pad 68: bank shift 4/row, float4-aligned
  int tid = threadIdx.x;
  for (int pp = 0; pp < 4; ++pp) {
    int f = (pp * 256 + tid) * 4;
    int cl = f >> 6, pl = f & 63;
    int c = c0 + cl;
    float4 v = *(const float4*)(x + ((size_t)(b * 512 + c)) * 4096 + p0 + pl);
    int g = c >> 4;
    float S    = stat[b * 32 + g];
    float SS   = stat[64 + b * 32 + g];
    float mean = S * (1.f / 65536.f);
    float var  = SS * (1.f / 65536.f) - mean * mean;
    float rstd = rsqrtf(var + 1e-5f);
    float w  = gnw[c] * rstd;
    float bb = gnb[c] - mean * w;
    tile[cl][pl + 0] = v.x * w + bb;
    tile[cl][pl + 1] = v.y * w + bb;
    tile[cl][pl + 2] = v.z * w + bb;
    tile[cl][pl + 3] = v.w * w + bb;
  }
  __syncthreads();
  for (int pp = 0; pp < 2; ++pp) {
    int f = (pp * 256 + tid) * 8;
    int pl = f >> 6, cl = f & 63;
    unsigned short u[8];
#pragma unroll
    for (int j = 0; j < 8; ++j) u[j] = f2b(tile[cl + j][pl]);
    *(uint4*)(t + ((size_t)(b * 4096 + p0 + pl)) * 512 + c0 + cl) = *(uint4*)u;
  }
}

// ---------------- 4. QKV GEMM ----------------
// Main-loop staging via global_load_lds (R7/R8-proven, R10: -5 us vs
// per-thread staging): unpadded [64][64] At/Bt, source col-block XOR-swizzled
// by row&7, frag reads apply the same XOR -> 2 lanes/bank (free). Epilogues
// untouched (they rewrite At after a barrier with their own indexing).
// q: [(bh*4096+p)*64+d] bf16 ; v: TRANSPOSED [bh][d][4096] bf16 ;
// K: FRAG-MAJOR Kp[bh][kb(32)][ig(8)][half(2)][lane(64)x8] bf16 — each 1 KB
// chunk is exactly one wave-wide A-frag load for attn (lane-contiguous 16 B).
__global__ __launch_bounds__(256) void gemm_qkv(
    const unsigned short* __restrict__ t, const unsigned short* __restrict__ Wqkv,
    const float* __restrict__ bqkv,
    unsigned short* __restrict__ qo, unsigned short* __restrict__ Kp,
    unsigned short* __restrict__ vo) {
  int M0 = blockIdx.x * 64;   // pixel 0..8128
  int N0 = blockIdx.y * 64;   // outch 0..1472
  __shared__ unsigned short At[64][64];
  __shared__ unsigned short Bt[64][64];
  int tid = threadIdx.x, w = tid >> 6, l = tid & 63;
  int quad = l >> 4, m16 = l & 15;
  // per-lane DMA source offsets (k0-invariant part). Chunk c = w*2+i covers
  // LDS rows 8c..8c+7; lane l -> row = 8c+(l>>3), col-block cb = l&7; source
  // col-block = cb ^ (row&7)  =>  LDS[row][cb] = SRC[row][cb^(row&7)].
  int offA[2], offB[2];
#pragma unroll
  for (int i = 0; i < 2; ++i) {
    int c = w * 2 + i;
    int row = 8 * c + (l >> 3);
    int cbs = ((l & 7) ^ (row & 7)) << 3;
    offA[i] = (M0 + row) * 512 + cbs;
    offB[i] = (N0 + row) * 512 + cbs;
  }
  int swa = m16 & 7;
  floatx4 acc[4] = {};
  for (int k0 = 0; k0 < 512; k0 += 64) {
    __syncthreads();
#pragma unroll
    for (int i = 0; i < 2; ++i) {
      int c = w * 2 + i;
      __builtin_amdgcn_global_load_lds(
          (const __attribute__((address_space(1))) unsigned int*)(t + offA[i] + k0),
          (__attribute__((address_space(3))) unsigned int*)(&At[0][0] + c * 512),
          16, 0, 0);
      __builtin_amdgcn_global_load_lds(
          (const __attribute__((address_space(1))) unsigned int*)(Wqkv + offB[i] + k0),
          (__attribute__((address_space(3))) unsigned int*)(&Bt[0][0] + c * 512),
          16, 0, 0);
    }
    __syncthreads();
    bf16x8 af0 = *(const bf16x8*)&At[w * 16 + m16][(quad ^ swa) << 3];
    bf16x8 af1 = *(const bf16x8*)&At[w * 16 + m16][((4 + quad) ^ swa) << 3];
#pragma unroll
    for (int nt = 0; nt < 4; ++nt) {
      bf16x8 b0 = *(const bf16x8*)&Bt[nt * 16 + m16][(quad ^ swa) << 3];
      bf16x8 b1 = *(const bf16x8*)&Bt[nt * 16 + m16][((4 + quad) ^ swa) << 3];
      acc[nt] = __builtin_amdgcn_mfma_f32_16x16x32_bf16(af0, b0, acc[nt], 0, 0, 0);
      acc[nt] = __builtin_amdgcn_mfma_f32_16x16x32_bf16(af1, b1, acc[nt], 0, 0, 0);
    }
  }
  int which = N0 >> 9;
  int head  = (N0 & 511) >> 6;
  if (which == 2) {
    // V: transpose 64x64 tile through LDS, store [bh][d][4096] coalesced
    __syncthreads();
#pragma unroll
    for (int nt = 0; nt < 4; ++nt) {
      int d = nt * 16 + m16;
      float bias = bqkv[N0 + d];
#pragma unroll
      for (int r = 0; r < 4; ++r)
        At[d][w * 16 + quad * 4 + r] = f2b(acc[nt][r] + bias);
    }
    __syncthreads();
    int bb = M0 >> 12, p0 = M0 & 4095;
    unsigned short* dst = vo + ((size_t)(bb * 8 + head) * 64) * 4096;
#pragma unroll
    for (int pp = 0; pp < 2; ++pp) {
      int f = (pp * 256 + tid) * 8;
      int d = f >> 6, pl = f & 63;
      *(uint4*)(dst + (size_t)d * 4096 + p0 + pl) = *(uint4*)&At[d][pl];
    }
  } else if (which == 1) {
    // K: repack to frag-major Kp. Stage [key_local][d] in LDS, read back in
    // frag order, store lane-contiguous 1 KB chunks.
    __syncthreads();
#pragma unroll
    for (int nt = 0; nt < 4; ++nt) {
      float bias = bqkv[N0 + nt * 16 + m16];
#pragma unroll
      for (int r = 0; r < 4; ++r)
        At[w * 16 + quad * 4 + r][nt * 16 + m16] = f2b(acc[nt][r] + bias);
    }
    __syncthreads();
    int bb = M0 >> 12, p = M0 & 4095;
    int kb = p >> 7, halfblk = (p >> 6) & 1;
    int ig = halfblk * 4 + w;             // ig = nt_g*2+hh, nt_g=halfblk*2+(w>>1), hh=w&1
    int ntl = w >> 1, hh = w & 1;
    int row = ntl * 32 + hh * 4 + ((m16 >> 2) << 3) + (m16 & 3);  // local key row
    size_t dstb = (((size_t)(bb * 8 + head) * 32 + kb) * 8 + ig) * 1024;
#pragma unroll
    for (int pp = 0; pp < 2; ++pp)
      *(uint4*)(Kp + dstb + pp * 512 + l * 8) = *(uint4*)&At[row][pp * 32 + quad * 8];
  } else {
    // Q: row-major per-head
#pragma unroll
    for (int nt = 0; nt < 4; ++nt) {
      int n = N0 + nt * 16 + m16;
      float bias = bqkv[n];
      int d = n & 63;
#pragma unroll
      for (int r = 0; r < 4; ++r) {
        int m = M0 + w * 16 + quad * 4 + r;   // pixel 0..8191
        int b = m >> 12, pp2 = m & 4095;
        qo[(((size_t)(b * 8 + head) * 4096 + pp2) << 6) + d] = f2b(acc[nt][r] + bias);
      }
    }
  }
}

// ---------------- 5. flash attention: K AND V staged via LDS DMA (R8 exact) ----------------
// R8 = 98.4 us (best attn). R9 (KVBLK=64+dbuf): +10.6 us — round-granularity
// overhead beats drain hiding. R10 (max-tree): +6.7 us — tree raised live
// registers (VGPR 52->56), chain latency was already hidden by other waves.
// Serial fmax chain + defer-max (T13) + K/V DMA staging is the operating point.
__global__ __launch_bounds__(256, 4) void attn(
    const unsigned short* __restrict__ q, const unsigned short* __restrict__ Kp,
    const unsigned short* __restrict__ vt,
    unsigned short* __restrict__ ob) {
  int qt = blockIdx.x;           // 0..63  (64-query tile)
  int bh = blockIdx.y;           // 0..15
  __shared__ unsigned short Klds[8192];     // 16 KB frag-major K block
  __shared__ unsigned short Vt[64][128];    // 16 KB [d][key16B-swz]
  int tid = threadIdx.x, w = tid >> 6, l = tid & 63;
  int quad = l >> 4, m16 = l & 15;
  const size_t vbase = (size_t)bh * HWN * DHD;

  // per-lane pre-swizzled V source offsets (kt-invariant). Chunk c=w*4+i is
  // LDS rows 4c..4c+3; lane l lands at row=4c+(l>>4), col block cb=l&15, so
  // source col block = cb ^ (row&15)  =>  LDS[row][cb] = V[row][cb^(row&15)].
  int goff[4];
#pragma unroll
  for (int i = 0; i < 4; ++i) {
    int c = w * 4 + i;
    int row = 4 * c + (l >> 4);
    int cbl = l & 15;
    goff[i] = row * 4096 + ((cbl ^ (row & 15)) << 3);
  }

  bf16x8 qf0, qf1;   // Q[qrow][quad*8+j] -> B-frag of K=32 mfma
  {
    int qrow = qt * 64 + w * 16 + m16;
    const unsigned short* qp = q + vbase + (size_t)qrow * 64 + quad * 8;
    qf0 = *(const bf16x8*)qp;
    qf1 = *(const bf16x8*)(qp + 32);
  }
  bf16x8 ones;
#pragma unroll
  for (int z = 0; z < 8; ++z) ones[z] = (short)0x3F80;   // 1.0 bf16

  floatx4 accO[4] = {};   // O[q=quad*4+i][d=dt*16+m16]
  floatx4 accL = {};      // l[q=quad*4+i]
  float mrow = -1e30f;    // per-lane running max, query = m16

  for (int kt = 0; kt < 32; ++kt) {
    __syncthreads();      // all waves done reading Klds/Vt of round kt-1
    // K block: 16 x 1KB chunks, 4 DMA per wave; frag-major source is already
    // lane-contiguous (lands exactly where QK^T reads: ig*1024(+512) + l*8).
    const unsigned short* kpb = Kp + (((size_t)bh * 32 + kt) * 8) * 1024;
    const unsigned short* vtile = vt + vbase + kt * 128;
#pragma unroll
    for (int i = 0; i < 4; ++i) {
      int c = w * 4 + i;
      __builtin_amdgcn_global_load_lds(
          (const __attribute__((address_space(1))) unsigned int*)(kpb + c * 512 + l * 8),
          (__attribute__((address_space(3))) unsigned int*)(Klds + c * 512),
          16, 0, 0);
      __builtin_amdgcn_global_load_lds(
          (const __attribute__((address_space(1))) unsigned int*)(vtile + goff[i]),
          (__attribute__((address_space(3))) unsigned int*)(&Vt[0][0] + c * 512),
          16, 0, 0);
    }
    __syncthreads();      // vmcnt(0) drain: K+V landed, ready for all waves
    // S^T = K * Q^T, K A-frags from LDS (permuted-key semantics:
    // s[ig][i] = S[q=m16][key = kt*128 + (ig>>1)*32 + quad*8 + (ig&1)*4 + i])
    const unsigned short* kl = Klds + l * 8;
    floatx4 s[8];
#pragma unroll
    for (int ig = 0; ig < 8; ++ig) {
      bf16x8 kf0 = *(const bf16x8*)(kl + ig * 1024);
      bf16x8 kf1 = *(const bf16x8*)(kl + ig * 1024 + 512);
      floatx4 z = {};
      z = __builtin_amdgcn_mfma_f32_16x16x32_bf16(kf0, qf0, z, 0, 0, 0);
      s[ig] = __builtin_amdgcn_mfma_f32_16x16x32_bf16(kf1, qf1, z, 0, 0, 0);
    }
    // online softmax: reduce across quads only (xor 16, 32)
    float mx = s[0][0];
#pragma unroll
    for (int ig = 0; ig < 8; ++ig)
#pragma unroll
      for (int i = 0; i < 4; ++i) mx = fmaxf(mx, s[ig][i]);
    mx = fmaxf(mx, __shfl_xor(mx, 16));
    mx = fmaxf(mx, __shfl_xor(mx, 32));
    // defer-max: only rescale when the max grows by > 8 (log2 domain);
    // otherwise keep mrow, P bounded by 2^8 = 256 (bf16-safe).
    bool grew = mx > mrow + 8.0f;
    if (__ballot(grew)) {
      float mnew = grew ? mx : mrow;
      float alpha = fast_exp2(mrow - mnew);   // 1.0 for lanes that didn't grow
      float al0 = __shfl(alpha, quad * 4 + 0);
      float al1 = __shfl(alpha, quad * 4 + 1);
      float al2 = __shfl(alpha, quad * 4 + 2);
      float al3 = __shfl(alpha, quad * 4 + 3);
#pragma unroll
      for (int dt = 0; dt < 4; ++dt) {
        accO[dt][0] *= al0; accO[dt][1] *= al1;
        accO[dt][2] *= al2; accO[dt][3] *= al3;
      }
      accL[0] *= al0; accL[1] *= al1; accL[2] *= al2; accL[3] *= al3;
      mrow = mnew;
    }
#pragma unroll
    for (int ig = 0; ig < 8; ++ig)
#pragma unroll
      for (int i = 0; i < 4; ++i)
        s[ig][i] = fast_exp2(s[ig][i] - mrow);
    // P -> bf16 A-frags (K=32): element j = hh*4+i from s[nt*2+hh][i]
    bf16x8 pf[4];
#pragma unroll
    for (int nt = 0; nt < 4; ++nt) {
      union { unsigned u[4]; bf16x8 v; } pu;
      pu.u[0] = pack_bf16_trunc(s[nt * 2][0],     s[nt * 2][1]);
      pu.u[1] = pack_bf16_trunc(s[nt * 2][2],     s[nt * 2][3]);
      pu.u[2] = pack_bf16_trunc(s[nt * 2 + 1][0], s[nt * 2 + 1][1]);
      pu.u[3] = pack_bf16_trunc(s[nt * 2 + 1][2], s[nt * 2 + 1][3]);
      pf[nt] = pu.v;
    }
    // O += P*V (K=32): B-frag = Vt[d=dt*16+m16][swizzled key block], 0-conflict
#pragma unroll
    for (int dt = 0; dt < 4; ++dt) {
#pragma unroll
      for (int nt = 0; nt < 4; ++nt) {
        bf16x8 vf = *(const bf16x8*)&Vt[dt * 16 + m16][((nt * 4 + quad) ^ m16) << 3];
        accO[dt] = __builtin_amdgcn_mfma_f32_16x16x32_bf16(pf[nt], vf, accO[dt], 0, 0, 0);
      }
    }
#pragma unroll
    for (int nt = 0; nt < 4; ++nt)
      accL = __builtin_amdgcn_mfma_f32_16x16x32_bf16(pf[nt], ones, accL, 0, 0, 0);
  }
  // ---- epilogue: normalized bf16 output straight to ob[(b*4096+q)*512+h*64+d] ----
  int b = bh >> 3, h = bh & 7;
  float li0 = 1.f / accL[0];
  float li1 = 1.f / accL[1];
  float li2 = 1.f / accL[2];
  float li3 = 1.f / accL[3];
  int qrow = qt * 64 + w * 16 + quad * 4;
  unsigned short* op = ob + ((size_t)(b * 4096 + qrow)) * 512 + h * 64;
#pragma unroll
  for (int dt = 0; dt < 4; ++dt) {
    int d = dt * 16 + m16;
    op[d]         = f2b(accO[dt][0] * li0);
    op[512 + d]   = f2b(accO[dt][1] * li1);
    op[1024 + d]  = f2b(accO[dt][2] * li2);
    op[1536 + d]  = f2b(accO[dt][3] * li3);
  }
}

// ---------------- 6. out-proj + bias + residual, coalesced fp32 store ----------------
// Same DMA-staged main loop as gemm_qkv (R10, kept).
__global__ __launch_bounds__(256) void gemm_out(
    const unsigned short* __restrict__ o, const unsigned short* __restrict__ Wp,
    const float* __restrict__ bp, const float* __restrict__ x,
    float* __restrict__ out) {
  int C0 = blockIdx.x * 64, P0 = blockIdx.y * 64, b = blockIdx.z;
  __shared__ unsigned short At[64][64];   // Wp rows (channel)
  __shared__ unsigned short Bt[64][64];   // o rows (pixel)
  int tid = threadIdx.x, w = tid >> 6, l = tid & 63;
  int quad = l >> 4, m16 = l & 15;
  int offA[2], offB[2];
#pragma unroll
  for (int i = 0; i < 2; ++i) {
    int c = w * 2 + i;
    int row = 8 * c + (l >> 3);
    int cbs = ((l & 7) ^ (row & 7)) << 3;
    offA[i] = (C0 + row) * 512 + cbs;
    offB[i] = (b * 4096 + P0 + row) * 512 + cbs;
  }
  int swa = m16 & 7;
  floatx4 acc[4] = {};
  for (int k0 = 0; k0 < 512; k0 += 64) {
    __syncthreads();
#pragma unroll
    for (int i = 0; i < 2; ++i) {
      int c = w * 2 + i;
      __builtin_amdgcn_global_load_lds(
          (const __attribute__((address_space(1))) unsigned int*)(Wp + offA[i] + k0),
          (__attribute__((address_space(3))) unsigned int*)(&At[0][0] + c * 512),
          16, 0, 0);
      __builtin_amdgcn_global_load_lds(
          (const __attribute__((address_space(1))) unsigned int*)(o + (size_t)offB[i] + k0),
          (__attribute__((address_space(3))) unsigned int*)(&Bt[0][0] + c * 512),
          16, 0, 0);
    }
    __syncthreads();
    bf16x8 af0 = *(const bf16x8*)&At[w * 16 + m16][(quad ^ swa) << 3];
    bf16x8 af1 = *(const bf16x8*)&At[w * 16 + m16][((4 + quad) ^ swa) << 3];
#pragma unroll
    for (int nt = 0; nt < 4; ++nt) {
      bf16x8 b0 = *(const bf16x8*)&Bt[nt * 16 + m16][(quad ^ swa) << 3];
      bf16x8 b1 = *(const bf16x8*)&Bt[nt * 16 + m16][((4 + quad) ^ swa) << 3];
      acc[nt] = __builtin_amdgcn_mfma_f32_16x16x32_bf16(af0, b0, acc[nt], 0, 0, 0);
      acc[nt] = __builtin_amdgcn_mfma_f32_16x16x32_bf16(af1, b1, acc[nt], 0, 0, 0);
    }
  }
#pragma unroll
  for (int r = 0; r < 4; ++r) {
    int c = C0 + w * 16 + quad * 4 + r;
    float bias = bp[c];
#pragma unroll
    for (int nt = 0; nt < 4; ++nt) {
      int p = P0 + nt * 16 + m16;
      size_t idx = ((size_t)(b * 512 + c)) * 4096 + p;
      out[idx] = acc[nt][r] + bias + x[idx];
    }
  }
}

extern "C" void kernel_launch(void* const* d_in, const int* in_sizes, int n_in,
                              void* d_out, int out_size, void* d_ws, size_t ws_size,
                              hipStream_t stream) {
  const float* x   = (const float*)d_in[0];
  const float* gnw = (const float*)d_in[1];
  const float* gnb = (const float*)d_in[2];
  const float* wq  = (const float*)d_in[3];
  const float* bq  = (const float*)d_in[4];
  const float* wk  = (const float*)d_in[5];
  const float* bk  = (const float*)d_in[6];
  const float* wv  = (const float*)d_in[7];
  const float* bv  = (const float*)d_in[8];
  const float* wp  = (const float*)d_in[9];
  const float* bp  = (const float*)d_in[10];
  float* out = (float*)d_out;

  char* ws = (char*)d_ws;
  float* stat          = (float*)ws;          ws += 1024;
  float* bqkv          = (float*)ws;          ws += 8192;
  unsigned short* Wqkv = (unsigned short*)ws; ws += (size_t)1536 * 512 * 2;
  unsigned short* Wp   = (unsigned short*)ws; ws += (size_t)512 * 512 * 2;
  unsigned short* t    = (unsigned short*)ws; ws += (size_t)8192 * 512 * 2;
  unsigned short* qb   = (unsigned short*)ws; ws += (size_t)8192 * 512 * 2;
  unsigned short* Kp   = (unsigned short*)ws; ws += (size_t)8192 * 512 * 2;  // frag-major K
  unsigned short* vb   = (unsigned short*)ws; ws += (size_t)8192 * 512 * 2;  // [16][64][4096]
  unsigned short* ob   = (unsigned short*)ws; ws += (size_t)8192 * 512 * 2;

  hipMemsetAsync(stat, 0, 512, stream);
  prep_gn<<<4615, 256, 0, stream>>>(x, stat, wq, wk, wv, wp, bq, bk, bv, Wqkv, Wp, bqkv);
  gn_apply<<<1024, 256, 0, stream>>>(x, stat, gnw, gnb, t);
  dim3 g1(128, 24);
  gemm_qkv<<<g1, 256, 0, stream>>>(t, Wqkv, bqkv, qb, Kp, vb);
  dim3 g2(64, 16);
  attn<<<g2, 256, 0, stream>>>(qb, Kp, vb, ob);
  dim3 g3(8, 64, 2);
  gemm_out<<<g3, 256, 0, stream>>>(ob, Wp, bp, x, out);
}